// Round 2
// baseline (168.106 us; speedup 1.0000x reference)
//
#include <hip/hip_runtime.h>
#include <math.h>

// HebbianMemory: x(8,2048,512) f32; k/v/q = x@W+b; scan:
//   mem_t = q_t @ state ; state = 0.9*state + 0.1*outer(k_t, v_t)
// out = mems@Wo+bo ; outputs: out (8,2048,512) then final_state (8,512,512).
//
// Banded-attention formulation (decay truncation lam^128=1.4e-6):
//   mem_j = [lam128 Qh Kh^T_{j-2} | lam64 Qh Kh^T_{j-1} | strictlow(Qh Kh^T_j)]
//           @ [V_{j-2}; V_{j-1}; V_j]            -- fully parallel over j
//   final_state = lam64 (G31 + lam64 (G30 + lam64 G29)),  G_j = Kh_j^T V_j
//
// GEMMs: 256x256 tile, BK=64, 8 waves, 4 quadrant-phases per K-tile
// (m201 template: T2 XOR-swizzled LDS + T3/T4 staged prefetch with
// boundary-only drain + T5 setprio around MFMA clusters). Stages of tile
// t+1 issue in phases 0/1 of tile t, so the boundary __syncthreads drain
// is cheap. khT is only consumed by fstate at t>=1856, so the transposed
// k-epilogue runs on 1/8 of m-tiles.
// R1 fix: epilogue col-base was wn&63 (==0 for all waves -> collisions +
// unwritten cols); correct is (w&1)*64.

#define DIMD 512
#define SEQL 2048
#define LRC 0.1f
#define LAM64 1.1790184577738602e-3f    // 0.9^64
#define LAM128 1.3900845237714473e-6f   // 0.9^128
#define L2LAM -0.15200309344504997f     // log2(0.9)

#define KVQ_ELEMS ((size_t)16384 * 512)   // 8388608
#define WSLAB ((size_t)512 * 512)

typedef __attribute__((ext_vector_type(8))) short bf16x8;
typedef __attribute__((ext_vector_type(4))) float f32x4;

__device__ __forceinline__ unsigned short f2bf(float f) {
  unsigned int u = __float_as_uint(f);
  u += 0x7FFFu + ((u >> 16) & 1u);
  return (unsigned short)(u >> 16);
}

// async global->LDS, 16B per lane; lds base must be wave-uniform
__device__ __forceinline__ void gload16(const unsigned short* g, char* l) {
  __builtin_amdgcn_global_load_lds(
      (const __attribute__((address_space(1))) unsigned int*)g,
      (__attribute__((address_space(3))) unsigned int*)l, 16, 0, 0);
}

// ---------------- prep: x->bf16 (blocks 0..8191) + W->W^T bf16 (8192..9215) --
__global__ __launch_bounds__(256) void prep(
    const float* __restrict__ x, unsigned short* __restrict__ Abf,
    const float* __restrict__ Wq, const float* __restrict__ Wk,
    const float* __restrict__ Wv, const float* __restrict__ Wo,
    unsigned short* __restrict__ T) {
  const int blk = blockIdx.x;
  if (blk < 8192) {
    const size_t idx = ((size_t)blk * 256 + threadIdx.x) * 4;
    float4 v = *(const float4*)(x + idx);
    ushort4 u;
    u.x = f2bf(v.x); u.y = f2bf(v.y); u.z = f2bf(v.z); u.w = f2bf(v.w);
    *(ushort4*)(Abf + idx) = u;
    return;
  }
  const int r2 = blk - 8192;     // 0..1023
  const int z = r2 >> 8;         // 0..3
  const int rem = r2 & 255;
  const int nb = (rem & 15) * 32, kb = (rem >> 4) * 32;
  const float* W = (z == 0) ? Wq : (z == 1) ? Wk : (z == 2) ? Wv : Wo;
  unsigned short* Tz = T + (size_t)z * WSLAB;
  __shared__ float tl[32][33];
  const int r = threadIdx.x >> 5, c = threadIdx.x & 31;
#pragma unroll
  for (int i = 0; i < 4; ++i)
    tl[r + i * 8][c] = W[(size_t)(kb + r + i * 8) * 512 + nb + c];
  __syncthreads();
#pragma unroll
  for (int i = 0; i < 4; ++i)
    Tz[(size_t)(nb + r + i * 8) * 512 + kb + c] = f2bf(tl[c][r + i * 8]);
}

// ---------------- bf16 MFMA GEMM: 256x256 tile, BK=64, 8 waves, 8-phase ------
// LDS arena 128KB: A[2][256][64]bf16 at 0, B[2][256][64] at 64K. Row line =
// 128B; byte col swizzled by ((row&7)<<4) (inverse applied on gload source).
// Per K-tile: 4 phases (kk,qm); phase = {ds_read 4-8 x b128 | stage half of
// tile t+1 | s_barrier | setprio(1) 16xMFMA setprio(0) | s_barrier}; tile
// boundary uses __syncthreads() (drains the 8 boundary-slack stage loads).
// EMODE 0 epilogue: z=0 q_hat; z=1 k_hat (+k_hatT on last tile per batch);
// z=2 vT. EMODE 1: f32 C+bias.
template <int EMODE>
__global__ __launch_bounds__(512, 2) void mfma_gemm(
    const unsigned short* __restrict__ A,
    const unsigned short* __restrict__ T,
    const float* __restrict__ b0, const float* __restrict__ b1,
    const float* __restrict__ b2,
    float* __restrict__ Cf,
    unsigned short* __restrict__ qh, unsigned short* __restrict__ kh,
    unsigned short* __restrict__ khT, unsigned short* __restrict__ vTp) {
  __shared__ __align__(16) char smem[131072];

  // XCD-chunked bijective swizzle (nwg % 8 == 0), n-fastest inside chunk so
  // the 6 (resp 2) n-tiles of an m-row share the A-panel in one XCD's L2.
  const int wg = blockIdx.x;
  int swz, mt, nt;
  if (EMODE == 0) {
    swz = (wg & 7) * 48 + (wg >> 3);       // nwg=384, q=48
    mt = swz / 6; nt = swz - mt * 6;
  } else {
    swz = (wg & 7) * 16 + (wg >> 3);       // nwg=128, q=16
    mt = swz >> 1; nt = swz & 1;
  }
  const int z = (EMODE == 0) ? (nt >> 1) : 0;
  const int nloc0 = (EMODE == 0) ? ((nt & 1) * 256) : (nt * 256);
  const int m0 = mt * 256;
  const unsigned short* Tz = T + (size_t)z * WSLAB;
  const float* bias = (z == 0) ? b0 : (z == 1) ? b1 : b2;

  const int tid = threadIdx.x;
  const int lane = tid & 63;
  const int w = tid >> 6;
  const int fr = lane & 15, fg = lane >> 4;
  const int wm = (w >> 2) * 128;   // 2 m-positions x 128 rows
  const int wn = (w & 3) * 64;     // 4 n-positions x 64 cols

  // ---- staging geometry: dest linear (base + lane*16); source pre-swizzled.
  const int srow = tid >> 3;                               // + s*64
  const int ecolx = ((tid & 7) * 8) ^ ((srow & 7) * 8);    // elems
  const unsigned short* As = A + (size_t)(m0 + srow) * DIMD + ecolx;
  const unsigned short* Bs = Tz + (size_t)(nloc0 + srow) * DIMD + ecolx;
  char* const sdA = smem + w * 1024;
  char* const sdB = smem + 65536 + w * 1024;

#define STAGE_A(KT, BUF)                                                  \
  { char* d = sdA + (BUF) * 32768;                                        \
    _Pragma("unroll") for (int s = 0; s < 4; ++s)                         \
      gload16(As + (size_t)(s * 64) * DIMD + (KT) * 64, d + s * 8192); }
#define STAGE_B(KT, BUF)                                                  \
  { char* d = sdB + (BUF) * 32768;                                        \
    _Pragma("unroll") for (int s = 0; s < 4; ++s)                         \
      gload16(Bs + (size_t)(s * 64) * DIMD + (KT) * 64, d + s * 8192); }

  // ---- fragment-read geometry: row line 128B, byte off ^= ((row&7)<<4).
  const int xsw = (fr & 7) << 4;
  const int offk0 = (fg * 16) ^ xsw;
  const int offk1 = (64 + fg * 16) ^ xsw;
  const int arow_off = (wm + fr) * 128;
  const int brow_off = (wn + fr) * 128;

  f32x4 acc[8][4];
  const f32x4 zf = {0.f, 0.f, 0.f, 0.f};
#pragma unroll
  for (int i = 0; i < 8; ++i)
#pragma unroll
    for (int j = 0; j < 4; ++j) acc[i][j] = zf;

  STAGE_A(0, 0);
  STAGE_B(0, 0);
  __syncthreads();  // drain prologue stages

  for (int kt = 0; kt < 8; ++kt) {
    const int cur = kt & 1;
    const char* pa = smem + cur * 32768 + arow_off;
    const char* pb = smem + 65536 + cur * 32768 + brow_off;
    bf16x8 bfr[4];
#pragma unroll
    for (int q = 0; q < 4; ++q) {        // (kk,qm) = (q>>1, q&1)
      const int qm = q & 1;
      const int offk = (q >> 1) ? offk1 : offk0;
      if (qm == 0) {
#pragma unroll
        for (int ni = 0; ni < 4; ++ni)
          bfr[ni] = *(const bf16x8*)(pb + ni * 2048 + offk);
      }
      bf16x8 af[4];
#pragma unroll
      for (int i = 0; i < 4; ++i)
        af[i] = *(const bf16x8*)(pa + (qm * 4 + i) * 2048 + offk);
      if (q == 0 && kt < 7) STAGE_A(kt + 1, cur ^ 1);
      if (q == 1 && kt < 7) STAGE_B(kt + 1, cur ^ 1);
      __builtin_amdgcn_s_barrier();      // pacing: align MFMA bursts
      __builtin_amdgcn_s_setprio(1);
#pragma unroll
      for (int i = 0; i < 4; ++i)
#pragma unroll
        for (int ni = 0; ni < 4; ++ni)
          acc[qm * 4 + i][ni] = __builtin_amdgcn_mfma_f32_16x16x32_bf16(
              af[i], bfr[ni], acc[qm * 4 + i][ni], 0, 0, 0);
      __builtin_amdgcn_s_setprio(0);
      if (q < 3) {
        __builtin_amdgcn_s_barrier();    // pacing: end phase window
      } else {
        __syncthreads();  // tile boundary: drains stages (2-3 phases slack)
      }
    }
  }
#undef STAGE_A
#undef STAGE_B

  const int orow = fg * 4;

  if (EMODE == 1) {
#pragma unroll
    for (int ni = 0; ni < 4; ++ni) {
      const int col = nloc0 + wn + ni * 16 + fr;
      const float bi = b0[col];
#pragma unroll
      for (int mi = 0; mi < 8; ++mi) {
        float* cp = Cf + (size_t)(m0 + wm + mi * 16 + orow) * 512 + col;
#pragma unroll
        for (int r = 0; r < 4; ++r) cp[(size_t)r * 512] = acc[mi][ni][r] + bi;
      }
    }
    return;
  }

  // ---- EMODE 0 epilogue: repack via LDS in 128-col halves ----
  unsigned short* cl = (unsigned short*)smem;
  const size_t batch = (size_t)(m0 >> 11);
  const int tl = m0 & 2047;
  const int chw = (w >> 1) & 1;    // this wave's col-half
  const int lcb = (w & 1) * 64;    // col base within the half (R1 fix)

  if (z <= 1) {
    __syncthreads();  // K-loop LDS dead; smem reusable
#pragma unroll
    for (int ch = 0; ch < 2; ++ch) {
      if (ch) __syncthreads();  // prev half's copy-out reads done
      if (chw == ch) {
#pragma unroll
        for (int ni = 0; ni < 4; ++ni) {
          const int lcol = lcb + ni * 16 + fr;
          const float bi = bias[nloc0 + ch * 128 + lcol];
#pragma unroll
          for (int mi = 0; mi < 8; ++mi) {
#pragma unroll
            for (int r = 0; r < 4; ++r) {
              const int row = wm + mi * 16 + orow + r;
              float v = acc[mi][ni][r] + bi;
              v *= (z == 0) ? exp2f(L2LAM * (float)(row & 63))
                            : LRC * exp2f(-L2LAM * (float)((row & 63) + 1));
              cl[row * 136 + lcol] = f2bf(v);
            }
          }
        }
      }
      __syncthreads();
      {
        const int row = tid >> 1, seg = tid & 1;
        unsigned short* dst = (z == 0 ? qh : kh) + (size_t)(m0 + row) * DIMD +
            nloc0 + ch * 128 + seg * 64;
        const unsigned short* sp = cl + row * 136 + seg * 64;
#pragma unroll
        for (int j2 = 0; j2 < 8; ++j2)
          *(float4*)(dst + j2 * 8) = *(const float4*)(sp + j2 * 8);
      }
    }
  }

  // transposed pass: vT always; khT only where fstate reads (t >= 1792)
  if (z == 2 || (z == 1 && tl == 1792)) {
    __syncthreads();
#pragma unroll
    for (int ch = 0; ch < 2; ++ch) {
      if (ch) __syncthreads();
      if (chw == ch) {
#pragma unroll
        for (int ni = 0; ni < 4; ++ni) {
          const int lcol = lcb + ni * 16 + fr;
          const float bi = bias[nloc0 + ch * 128 + lcol];
#pragma unroll
          for (int mi = 0; mi < 8; ++mi) {
#pragma unroll
            for (int r = 0; r < 4; ++r) {
              const int row = wm + mi * 16 + orow + r;
              float v = acc[mi][ni][r] + bi;
              if (z == 1) v *= LRC * exp2f(-L2LAM * (float)((row & 63) + 1));
              cl[lcol * 264 + row] = f2bf(v);
            }
          }
        }
      }
      __syncthreads();
      {
        const int col = tid >> 2, rseg = tid & 3;
        unsigned short* dstT = (z == 1 ? khT : vTp) +
            batch * ((size_t)DIMD * SEQL) +
            (size_t)(nloc0 + ch * 128 + col) * SEQL + tl + rseg * 64;
        const unsigned short* sp = cl + col * 264 + rseg * 64;
#pragma unroll
        for (int j2 = 0; j2 < 8; ++j2)
          *(float4*)(dstT + j2 * 8) = *(const float4*)(sp + j2 * 8);
      }
    }
  }
}

// ---------------- banded attention + fused final-state ----------------
// blocks 0..511: battn (2 e-halves x 32 t-blocks x 8 batches), 4 waves.
// blocks 512..639: final_state = lam64(G31 + lam64(G30 + lam64 G29)).
__global__ __launch_bounds__(256) void battn(
    const unsigned short* __restrict__ qh, const unsigned short* __restrict__ kh,
    const unsigned short* __restrict__ vTp, const unsigned short* __restrict__ khT,
    unsigned short* __restrict__ mbf, float* __restrict__ fstate) {
  const int blk = blockIdx.x;
  const int tid = threadIdx.x;
  const int lane = tid & 63;
  const int w = tid >> 6;
  const int fr = lane & 15;
  const int fg = lane >> 4;

  __shared__ __align__(16) char Kl[65536];              // K_sb [64][1024B] swz
  __shared__ __align__(16) unsigned short Pl[64 * 72];  // P [t][s], stride 72

  if (blk >= 512) {
    // ---- fstatek path ----
    const int b2 = blk - 512;
    const int b = b2 & 7;
    const int slab = b2 >> 3;  // 0..15
    const int e0g = slab * 32;
    const int wd0 = w * 128;
    const unsigned short* kTb = khT + (size_t)b * DIMD * SEQL;
    const unsigned short* vTb = vTp + (size_t)b * DIMD * SEQL;

    f32x4 S[8][2];
    const f32x4 zf = {0.f, 0.f, 0.f, 0.f};
#pragma unroll
    for (int mi = 0; mi < 8; ++mi)
#pragma unroll
      for (int ni = 0; ni < 2; ++ni) S[mi][ni] = zf;

#pragma unroll
    for (int tb = 29; tb < 32; ++tb) {
      const int t0 = tb * 64;
#pragma unroll
      for (int ks2 = 0; ks2 < 2; ++ks2) {
        bf16x8 aK[8], bV[2];
#pragma unroll
        for (int mi = 0; mi < 8; ++mi)
          aK[mi] = *(const bf16x8*)(kTb + (size_t)(wd0 + mi * 16 + fr) * SEQL +
                                    t0 + ks2 * 32 + fg * 8);
#pragma unroll
        for (int ni = 0; ni < 2; ++ni)
          bV[ni] = *(const bf16x8*)(vTb + (size_t)(e0g + ni * 16 + fr) * SEQL +
                                    t0 + ks2 * 32 + fg * 8);
#pragma unroll
        for (int mi = 0; mi < 8; ++mi)
#pragma unroll
          for (int ni = 0; ni < 2; ++ni)
            S[mi][ni] = __builtin_amdgcn_mfma_f32_16x16x32_bf16(aK[mi], bV[ni],
                                                                S[mi][ni], 0, 0, 0);
      }
#pragma unroll
      for (int mi = 0; mi < 8; ++mi)
#pragma unroll
        for (int ni = 0; ni < 2; ++ni) {
          S[mi][ni][0] *= LAM64;
          S[mi][ni][1] *= LAM64;
          S[mi][ni][2] *= LAM64;
          S[mi][ni][3] *= LAM64;
        }
    }
    float* fs = fstate + (size_t)b * DIMD * DIMD;
#pragma unroll
    for (int mi = 0; mi < 8; ++mi)
#pragma unroll
      for (int ni = 0; ni < 2; ++ni) {
        const int e = e0g + ni * 16 + fr;
#pragma unroll
        for (int r = 0; r < 4; ++r) {
          const int d = w * 128 + mi * 16 + fg * 4 + r;
          fs[(size_t)d * DIMD + e] = S[mi][ni][r];
        }
      }
    return;
  }

  // ---- battn path ----
  const int b = blk & 7;
  const int rest = blk >> 3;
  const int j = rest & 31;
  const int h = rest >> 5;
  const int t0 = j * 64;
  const int e0g = h * 256;
  const int wt0 = w * 16;
  const int nstartb = (j >= 2) ? 0 : (2 - j);  // first valid s-block (of 3)

  const unsigned short* qb = qh + (size_t)b * SEQL * DIMD;
  const unsigned short* kb = kh + (size_t)b * SEQL * DIMD;
  const unsigned short* vTb = vTp + (size_t)b * DIMD * SEQL;
  unsigned short* mb = mbf + (size_t)b * SEQL * DIMD;

  const int selem = lane * 8;  // 16B seg per lane, in elems

#define STAGE(S0)                                                            \
  {                                                                          \
    _Pragma("unroll") for (int c = 0; c < 16; ++c) {                         \
      const int row = w * 16 + c;                                            \
      gload16(kb + (size_t)((S0) + row) * DIMD + (selem ^ ((row & 7) << 3)), \
              Kl + row * 1024);                                              \
    }                                                                        \
  }

  // prologue: stage first s-block
  STAGE(t0 - 128 + nstartb * 64);

  // hoist Q fragments (per-wave-own t-rows, reused across s-blocks)
  bf16x8 aq[16];
  {
    const unsigned short* qrow = qb + (size_t)(t0 + wt0 + fr) * DIMD + fg * 8;
#pragma unroll
    for (int ks = 0; ks < 16; ++ks) aq[ks] = *(const bf16x8*)(qrow + ks * 32);
  }

  f32x4 mem[4][4];
  const f32x4 zf = {0.f, 0.f, 0.f, 0.f};
#pragma unroll
  for (int mi = 0; mi < 4; ++mi)
#pragma unroll
    for (int ni = 0; ni < 4; ++ni) mem[mi][ni] = zf;

  const int ew = e0g + w * 64;  // this wave's e-stripe for PV

  for (int sb = nstartb; sb < 3; ++sb) {
    const int s0 = t0 - 128 + sb * 64;
    __syncthreads();  // K(sb) resident (vmcnt drained); Pl free

    // ---- P = Qh @ K_sb^T (K from LDS) ----
    f32x4 P[4];
#pragma unroll
    for (int ni = 0; ni < 4; ++ni) P[ni] = zf;
#pragma unroll
    for (int ks = 0; ks < 16; ++ks) {
      bf16x8 bK[4];
#pragma unroll
      for (int ni = 0; ni < 4; ++ni) {
        const int row = ni * 16 + fr;
        bK[ni] = *(const bf16x8*)(Kl + row * 1024 +
                                  ((ks * 64 + fg * 16) ^ ((row & 7) << 4)));
      }
#pragma unroll
      for (int ni = 0; ni < 4; ++ni)
        P[ni] = __builtin_amdgcn_mfma_f32_16x16x32_bf16(aq[ks], bK[ni], P[ni], 0, 0, 0);
    }

    // ---- weight + write P to LDS (own t-rows) ----
#pragma unroll
    for (int ni = 0; ni < 4; ++ni) {
      const int s = ni * 16 + fr;
#pragma unroll
      for (int r = 0; r < 4; ++r) {
        const int t = wt0 + fg * 4 + r;
        float v = (sb == 0) ? P[ni][r] * LAM128
                : (sb == 1) ? P[ni][r] * LAM64
                            : ((s < t) ? P[ni][r] : 0.f);
        Pl[t * 72 + s] = f2bf(v);
      }
    }
    __syncthreads();  // P ready; all Kl reads done
    if (sb + 1 < 3) STAGE(s0 + 64);  // async stage overlaps PV

    // ---- mem += P @ V_sb : all 64 t-rows x own 64 e-cols ----
#pragma unroll
    for (int ks2 = 0; ks2 < 2; ++ks2) {
      bf16x8 ap[4];
#pragma unroll
      for (int mi = 0; mi < 4; ++mi)
        ap[mi] = *(const bf16x8*)(Pl + (mi * 16 + fr) * 72 + ks2 * 32 + fg * 8);
      const int tk = s0 + ks2 * 32 + fg * 8;
#pragma unroll
      for (int ni = 0; ni < 4; ++ni) {
        bf16x8 bV = *(const bf16x8*)(vTb + (size_t)(ew + ni * 16 + fr) * SEQL + tk);
#pragma unroll
        for (int mi = 0; mi < 4; ++mi)
          mem[mi][ni] = __builtin_amdgcn_mfma_f32_16x16x32_bf16(ap[mi], bV,
                                                               mem[mi][ni], 0, 0, 0);
      }
    }
  }
#undef STAGE

  // store mems bf16: all 64 t x own e-stripe
#pragma unroll
  for (int mi = 0; mi < 4; ++mi)
#pragma unroll
    for (int ni = 0; ni < 4; ++ni)
#pragma unroll
      for (int r = 0; r < 4; ++r) {
        const int t = t0 + mi * 16 + fg * 4 + r;
        mb[(size_t)t * DIMD + ew + ni * 16 + fr] = f2bf(mem[mi][ni][r]);
      }
}

extern "C" void kernel_launch(void* const* d_in, const int* in_sizes, int n_in,
                              void* d_out, int out_size, void* d_ws,
                              size_t ws_size, hipStream_t stream) {
  const float* x  = (const float*)d_in[0];
  const float* Wk = (const float*)d_in[1];
  const float* bk = (const float*)d_in[2];
  const float* Wv = (const float*)d_in[3];
  const float* bv = (const float*)d_in[4];
  const float* Wq = (const float*)d_in[5];
  const float* bq = (const float*)d_in[6];
  const float* Wo = (const float*)d_in[7];
  const float* bo = (const float*)d_in[8];

  float* outp = (float*)d_out;
  float* fstate = outp + KVQ_ELEMS;

  // ws layout (~86 MB):
  unsigned short* qhb = (unsigned short*)d_ws;          // q_hat [b][t][d]
  unsigned short* khb = qhb + KVQ_ELEMS;                // k_hat [b][t][d]
  unsigned short* khT = qhb + 2 * KVQ_ELEMS;            // k_hat^T [b][d][t] (t>=1792 only)
  unsigned short* vTp = qhb + 3 * KVQ_ELEMS;            // v^T [b][e][t]
  unsigned short* mbf = qhb + 4 * KVQ_ELEMS;            // mems bf16 [b][t][e]
  unsigned short* WT  = qhb + 5 * KVQ_ELEMS;            // W^T bf16 x4

  // pre-scan scratch inside d_out (dead until out-gemm writes it):
  unsigned short* Abf = (unsigned short*)d_out;         // x bf16 (16.8 MB)

  // 1) x -> bf16  +  W -> W^T bf16 (merged)
  prep<<<dim3(9216), 256, 0, stream>>>(x, Abf, Wq, Wk, Wv, Wo, WT);
  // 2) projections: merged N=1536 (q|k|v), 64 m-tiles x 6 n-tiles = 384 blocks
  mfma_gemm<0><<<dim3(384), 512, 0, stream>>>(
      Abf, WT, bq, bk, bv, nullptr, qhb, khb, khT, vTp);
  // 3) banded attention -> mems bf16 (blocks 0..511) + final_state (512..639)
  battn<<<dim3(640), 256, 0, stream>>>(qhb, khb, vTp, khT, mbf, fstate);
  // 4) out = mems @ Wo + bo : 64 m-tiles x 2 n-tiles = 128 blocks
  mfma_gemm<1><<<dim3(128), 512, 0, stream>>>(
      mbf, WT + 3 * WSLAB, bo, bo, bo, outp, nullptr, nullptr, nullptr, nullptr);
}

// Round 3
// 121.236 us; speedup vs baseline: 1.3866x; 1.3866x over previous
//
#include <hip/hip_runtime.h>
#include <math.h>

// HebbianMemory: x(8,2048,512) f32; k/v/q = x@W+b; scan:
//   mem_t = q_t @ state ; state = 0.9*state + 0.1*outer(k_t, v_t)
// out = mems@Wo+bo ; outputs: out (8,2048,512) then final_state (8,512,512).
//
// Banded-attention formulation (decay truncation lam^128=1.4e-6):
//   mem_j = [lam128 Qh Kh^T_{j-2} | lam64 Qh Kh^T_{j-1} | strictlow(Qh Kh^T_j)]
//           @ [V_{j-2}; V_{j-1}; V_j]            -- fully parallel over j
//   final_state = lam64 (G31 + lam64 (G30 + lam64 G29)),  G_j = Kh_j^T V_j
// GEMMs: round-15 structure (BK=32 dbuf, 128x128, packed-line swizzle) +
// T4 counted vmcnt: raw s_barrier + s_waitcnt vmcnt(4) keeps next-tile
// global_load_lds in flight across the barrier (no vmcnt(0) drain).
// R3: reverted from the failed 256x256 8-phase port (105us, 1 blk/CU,
// boundary vmcnt(0) drain exposed; see journal). Single safe delta vs the
// 123.4us baseline: khT trim -- fstate only reads k_hat^T at t>=1856, so
// the z=1 transposed epilogue runs only on tiles tl>=1792 (2/16 per batch),
// saving ~14.7 MB writes + pass-B VALU on 448 of 512 z=1 blocks.

#define DIMD 512
#define SEQL 2048
#define LRC 0.1f
#define LAM64 1.1790184577738602e-3f    // 0.9^64
#define LAM128 1.3900845237714473e-6f   // 0.9^128
#define L2LAM -0.15200309344504997f     // log2(0.9)

#define KVQ_ELEMS ((size_t)16384 * 512)   // 8388608
#define WSLAB ((size_t)512 * 512)

typedef __attribute__((ext_vector_type(8))) short bf16x8;
typedef __attribute__((ext_vector_type(4))) float f32x4;

__device__ __forceinline__ unsigned short f2bf(float f) {
  unsigned int u = __float_as_uint(f);
  u += 0x7FFFu + ((u >> 16) & 1u);
  return (unsigned short)(u >> 16);
}

// async global->LDS, 16B per lane; lds base must be wave-uniform
__device__ __forceinline__ void gload16(const unsigned short* g, char* l) {
  __builtin_amdgcn_global_load_lds(
      (const __attribute__((address_space(1))) unsigned int*)g,
      (__attribute__((address_space(3))) unsigned int*)l, 16, 0, 0);
}

// ---------------- prep: x->bf16 (blocks 0..8191) + W->W^T bf16 (8192..9215) --
__global__ __launch_bounds__(256) void prep(
    const float* __restrict__ x, unsigned short* __restrict__ Abf,
    const float* __restrict__ Wq, const float* __restrict__ Wk,
    const float* __restrict__ Wv, const float* __restrict__ Wo,
    unsigned short* __restrict__ T) {
  const int blk = blockIdx.x;
  if (blk < 8192) {
    const size_t idx = ((size_t)blk * 256 + threadIdx.x) * 4;
    float4 v = *(const float4*)(x + idx);
    ushort4 u;
    u.x = f2bf(v.x); u.y = f2bf(v.y); u.z = f2bf(v.z); u.w = f2bf(v.w);
    *(ushort4*)(Abf + idx) = u;
    return;
  }
  const int r2 = blk - 8192;     // 0..1023
  const int z = r2 >> 8;         // 0..3
  const int rem = r2 & 255;
  const int nb = (rem & 15) * 32, kb = (rem >> 4) * 32;
  const float* W = (z == 0) ? Wq : (z == 1) ? Wk : (z == 2) ? Wv : Wo;
  unsigned short* Tz = T + (size_t)z * WSLAB;
  __shared__ float tl[32][33];
  const int r = threadIdx.x >> 5, c = threadIdx.x & 31;
#pragma unroll
  for (int i = 0; i < 4; ++i)
    tl[r + i * 8][c] = W[(size_t)(kb + r + i * 8) * 512 + nb + c];
  __syncthreads();
#pragma unroll
  for (int i = 0; i < 4; ++i)
    Tz[(size_t)(nb + r + i * 8) * 512 + kb + c] = f2bf(tl[c][r + i * 8]);
}

// ---------------- bf16 MFMA GEMM (128x128 tile, BK=32, 4 waves) ----------------
// Double-buffered, ISSUE-ahead, counted vmcnt (T4). LDS: A[2][8K] at 0,
// B[2][8K] at 16K. Line = 2 packed rows (128B); read off ^ ((line&7)<<4),
// inverse on gload source.
// EMODE 0 epilogue: z=0 q_hat; z=1 k_hat (+k_hatT on tl>=1792); z=2 vT.
// EMODE 1: f32 C+bias.
template <int EMODE>
__global__ __launch_bounds__(256) void mfma_gemm(
    const unsigned short* __restrict__ A, int astr,
    const unsigned short* __restrict__ T0, const unsigned short* __restrict__ T1,
    const unsigned short* __restrict__ T2, int tstr,
    const float* __restrict__ b0, const float* __restrict__ b1,
    const float* __restrict__ b2,
    float* __restrict__ Cf,
    unsigned short* __restrict__ qh, unsigned short* __restrict__ kh,
    unsigned short* __restrict__ khT, unsigned short* __restrict__ vTp,
    int nkt) {
  const int z = blockIdx.z;
  const unsigned short* T = (z == 0) ? T0 : (z == 1) ? T1 : T2;
  const float* bias = (z == 0) ? b0 : (z == 1) ? b1 : b2;

  const int m0 = blockIdx.x * 128;
  const int n0 = blockIdx.y * 128;
  const int tid = threadIdx.x;
  const int lane = tid & 63;
  const int w = tid >> 6;
  const int wm = (w & 1) * 64;
  const int wn = (w >> 1) * 64;

  // dbuf 32KB; EMODE 0 epilogue reuses as cl[128][136] bf16 (34816B)
  __shared__ __align__(16) char smem[EMODE == 0 ? 35840 : 32768];

  f32x4 acc[4][4];
  const f32x4 zf = {0.f, 0.f, 0.f, 0.f};
#pragma unroll
  for (int i = 0; i < 4; ++i)
#pragma unroll
    for (int j = 0; j < 4; ++j) acc[i][j] = zf;

  // ---- staging geometry (per lane): dest L = lane*16 within wave's 2KB ----
  const int lr = lane >> 3;
  const int lo3 = lane & 7;
  const int xr = lo3 ^ lr;
  const int mbase = w * 32 + lr * 2 + (xr >> 2);
  const int kel = (xr & 3) * 8;
  const unsigned short* Ag = A + (size_t)(m0 + mbase) * astr + kel;
  const unsigned short* Tg = T + (size_t)(n0 + mbase) * tstr + kel;

#define ISSUE(KT, BUF)                                                     \
  {                                                                        \
    char* ab = smem + (BUF) * 8192 + w * 2048;                             \
    char* bb_ = smem + 16384 + (BUF) * 8192 + w * 2048;                    \
    _Pragma("unroll") for (int c = 0; c < 2; ++c) {                        \
      gload16(Ag + (size_t)(c * 16) * astr + (KT) * 32, ab + c * 1024);    \
      gload16(Tg + (size_t)(c * 16) * tstr + (KT) * 32, bb_ + c * 1024);   \
    }                                                                      \
  }

  // ---- fragment-read geometry ----
  const int fr = lane & 15;
  const int fg = lane >> 4;
  const int foff = ((((fr & 1) << 6) | (fg << 4)) ^ (((fr >> 1) & 7) << 4));
  const int aline = (wm >> 1) + (fr >> 1);
  const int bline = (wn >> 1) + (fr >> 1);

  ISSUE(0, 0);
  int bb = 0;
  for (int kt = 0; kt < nkt; ++kt) {
    if (kt + 1 < nkt) {
      ISSUE(kt + 1, bb ^ 1);  // 4 more in flight (8 total)
      asm volatile("s_waitcnt vmcnt(4)" ::: "memory");  // tile kt resident
    } else {
      asm volatile("s_waitcnt vmcnt(0)" ::: "memory");
    }
    __builtin_amdgcn_sched_barrier(0);
    __builtin_amdgcn_s_barrier();   // all waves' tile-kt loads landed
    const char* pa = smem + bb * 8192 + aline * 128 + foff;
    const char* pb = smem + 16384 + bb * 8192 + bline * 128 + foff;
    bf16x8 af[4], bfr[4];
#pragma unroll
    for (int mi = 0; mi < 4; ++mi) af[mi] = *(const bf16x8*)(pa + mi * 1024);
#pragma unroll
    for (int ni = 0; ni < 4; ++ni) bfr[ni] = *(const bf16x8*)(pb + ni * 1024);
#pragma unroll
    for (int mi = 0; mi < 4; ++mi)
#pragma unroll
      for (int ni = 0; ni < 4; ++ni)
        acc[mi][ni] = __builtin_amdgcn_mfma_f32_16x16x32_bf16(
            af[mi], bfr[ni], acc[mi][ni], 0, 0, 0);
    __builtin_amdgcn_s_barrier();   // all reads of buf bb done (lgkm drained by MFMA deps)
    __builtin_amdgcn_sched_barrier(0);
    bb ^= 1;
  }
#undef ISSUE

  const int orow = fg * 4;

  if (EMODE == 1) {
#pragma unroll
    for (int ni = 0; ni < 4; ++ni) {
      const int col = n0 + wn + ni * 16 + fr;
      const float bi = bias[col];
#pragma unroll
      for (int mi = 0; mi < 4; ++mi) {
        float* cp = Cf + (size_t)(m0 + wm + mi * 16 + orow) * 512 + col;
#pragma unroll
        for (int r = 0; r < 4; ++r) cp[(size_t)r * 512] = acc[mi][ni][r] + bi;
      }
    }
    return;
  }

  __syncthreads();  // full drain; smem reusable
  unsigned short* cl = (unsigned short*)smem;  // [128][136]
  const size_t batch = (size_t)(m0 >> 11);
  const int tl = m0 & 2047;

  if (z <= 1) {
    // pass A: row-major [row][col]
#pragma unroll
    for (int ni = 0; ni < 4; ++ni) {
      const int col = wn + ni * 16 + fr;
      const float bi = bias[n0 + col];
#pragma unroll
      for (int mi = 0; mi < 4; ++mi) {
#pragma unroll
        for (int r = 0; r < 4; ++r) {
          const int row = wm + mi * 16 + orow + r;
          float v = acc[mi][ni][r] + bi;
          v *= (z == 0) ? exp2f(L2LAM * (float)(row & 63))
                        : LRC * exp2f(-L2LAM * (float)((row & 63) + 1));
          cl[row * 136 + col] = f2bf(v);
        }
      }
    }
    __syncthreads();
    {
      const int row = tid >> 1, half = tid & 1;
      unsigned short* dst = (z == 0 ? qh : kh) +
          (size_t)(m0 + row) * DIMD + n0 + half * 64;
      const unsigned short* sp = cl + row * 136 + half * 64;
#pragma unroll
      for (int j = 0; j < 8; ++j)
        *(float4*)(dst + j * 8) = *(const float4*)(sp + j * 8);
    }
  }
  // transposed pass: vT always; khT only where fstate reads (t >= 1856)
  if (z == 2 || (z == 1 && tl >= 1792)) {
    __syncthreads();  // pass A reads done before overwrite
    // pass B: col-major [col][row]
#pragma unroll
    for (int ni = 0; ni < 4; ++ni) {
      const int col = wn + ni * 16 + fr;
      const float bi = bias[n0 + col];
#pragma unroll
      for (int mi = 0; mi < 4; ++mi) {
#pragma unroll
        for (int r = 0; r < 4; ++r) {
          const int row = wm + mi * 16 + orow + r;
          float v = acc[mi][ni][r] + bi;
          if (z == 1) v *= LRC * exp2f(-L2LAM * (float)((row & 63) + 1));
          cl[col * 136 + row] = f2bf(v);
        }
      }
    }
    __syncthreads();
    {
      const int col = tid >> 1, half = tid & 1;
      unsigned short* dstT = (z == 1 ? khT : vTp) + batch * DIMD * SEQL +
          (size_t)(n0 + col) * SEQL + tl + half * 64;
      const unsigned short* sp = cl + col * 136 + half * 64;
#pragma unroll
      for (int j = 0; j < 8; ++j)
        *(float4*)(dstT + j * 8) = *(const float4*)(sp + j * 8);
    }
  }
}

// ---------------- banded attention + fused final-state ----------------
// blocks 0..511: battn (2 e-halves x 32 t-blocks x 8 batches), 4 waves.
// blocks 512..639: final_state = lam64(G31 + lam64(G30 + lam64 G29)).
__global__ __launch_bounds__(256) void battn(
    const unsigned short* __restrict__ qh, const unsigned short* __restrict__ kh,
    const unsigned short* __restrict__ vTp, const unsigned short* __restrict__ khT,
    unsigned short* __restrict__ mbf, float* __restrict__ fstate) {
  const int blk = blockIdx.x;
  const int tid = threadIdx.x;
  const int lane = tid & 63;
  const int w = tid >> 6;
  const int fr = lane & 15;
  const int fg = lane >> 4;

  __shared__ __align__(16) char Kl[65536];              // K_sb [64][1024B] swz
  __shared__ __align__(16) unsigned short Pl[64 * 72];  // P [t][s], stride 72

  if (blk >= 512) {
    // ---- fstatek path ----
    const int b2 = blk - 512;
    const int b = b2 & 7;
    const int slab = b2 >> 3;  // 0..15
    const int e0g = slab * 32;
    const int wd0 = w * 128;
    const unsigned short* kTb = khT + (size_t)b * DIMD * SEQL;
    const unsigned short* vTb = vTp + (size_t)b * DIMD * SEQL;

    f32x4 S[8][2];
    const f32x4 zf = {0.f, 0.f, 0.f, 0.f};
#pragma unroll
    for (int mi = 0; mi < 8; ++mi)
#pragma unroll
      for (int ni = 0; ni < 2; ++ni) S[mi][ni] = zf;

#pragma unroll
    for (int tb = 29; tb < 32; ++tb) {
      const int t0 = tb * 64;
#pragma unroll
      for (int ks2 = 0; ks2 < 2; ++ks2) {
        bf16x8 aK[8], bV[2];
#pragma unroll
        for (int mi = 0; mi < 8; ++mi)
          aK[mi] = *(const bf16x8*)(kTb + (size_t)(wd0 + mi * 16 + fr) * SEQL +
                                    t0 + ks2 * 32 + fg * 8);
#pragma unroll
        for (int ni = 0; ni < 2; ++ni)
          bV[ni] = *(const bf16x8*)(vTb + (size_t)(e0g + ni * 16 + fr) * SEQL +
                                    t0 + ks2 * 32 + fg * 8);
#pragma unroll
        for (int mi = 0; mi < 8; ++mi)
#pragma unroll
          for (int ni = 0; ni < 2; ++ni)
            S[mi][ni] = __builtin_amdgcn_mfma_f32_16x16x32_bf16(aK[mi], bV[ni],
                                                                S[mi][ni], 0, 0, 0);
      }
#pragma unroll
      for (int mi = 0; mi < 8; ++mi)
#pragma unroll
        for (int ni = 0; ni < 2; ++ni) {
          S[mi][ni][0] *= LAM64;
          S[mi][ni][1] *= LAM64;
          S[mi][ni][2] *= LAM64;
          S[mi][ni][3] *= LAM64;
        }
    }
    float* fs = fstate + (size_t)b * DIMD * DIMD;
#pragma unroll
    for (int mi = 0; mi < 8; ++mi)
#pragma unroll
      for (int ni = 0; ni < 2; ++ni) {
        const int e = e0g + ni * 16 + fr;
#pragma unroll
        for (int r = 0; r < 4; ++r) {
          const int d = w * 128 + mi * 16 + fg * 4 + r;
          fs[(size_t)d * DIMD + e] = S[mi][ni][r];
        }
      }
    return;
  }

  // ---- battn path ----
  const int b = blk & 7;
  const int rest = blk >> 3;
  const int j = rest & 31;
  const int h = rest >> 5;
  const int t0 = j * 64;
  const int e0g = h * 256;
  const int wt0 = w * 16;
  const int nstartb = (j >= 2) ? 0 : (2 - j);  // first valid s-block (of 3)

  const unsigned short* qb = qh + (size_t)b * SEQL * DIMD;
  const unsigned short* kb = kh + (size_t)b * SEQL * DIMD;
  const unsigned short* vTb = vTp + (size_t)b * DIMD * SEQL;
  unsigned short* mb = mbf + (size_t)b * SEQL * DIMD;

  const int selem = lane * 8;  // 16B seg per lane, in elems

#define STAGE(S0)                                                            \
  {                                                                          \
    _Pragma("unroll") for (int c = 0; c < 16; ++c) {                         \
      const int row = w * 16 + c;                                            \
      gload16(kb + (size_t)((S0) + row) * DIMD + (selem ^ ((row & 7) << 3)), \
              Kl + row * 1024);                                              \
    }                                                                        \
  }

  // prologue: stage first s-block
  STAGE(t0 - 128 + nstartb * 64);

  // hoist Q fragments (per-wave-own t-rows, reused across s-blocks)
  bf16x8 aq[16];
  {
    const unsigned short* qrow = qb + (size_t)(t0 + wt0 + fr) * DIMD + fg * 8;
#pragma unroll
    for (int ks = 0; ks < 16; ++ks) aq[ks] = *(const bf16x8*)(qrow + ks * 32);
  }

  f32x4 mem[4][4];
  const f32x4 zf = {0.f, 0.f, 0.f, 0.f};
#pragma unroll
  for (int mi = 0; mi < 4; ++mi)
#pragma unroll
    for (int ni = 0; ni < 4; ++ni) mem[mi][ni] = zf;

  const int ew = e0g + w * 64;  // this wave's e-stripe for PV

  for (int sb = nstartb; sb < 3; ++sb) {
    const int s0 = t0 - 128 + sb * 64;
    __syncthreads();  // K(sb) resident (vmcnt drained); Pl free

    // ---- P = Qh @ K_sb^T (K from LDS) ----
    f32x4 P[4];
#pragma unroll
    for (int ni = 0; ni < 4; ++ni) P[ni] = zf;
#pragma unroll
    for (int ks = 0; ks < 16; ++ks) {
      bf16x8 bK[4];
#pragma unroll
      for (int ni = 0; ni < 4; ++ni) {
        const int row = ni * 16 + fr;
        bK[ni] = *(const bf16x8*)(Kl + row * 1024 +
                                  ((ks * 64 + fg * 16) ^ ((row & 7) << 4)));
      }
#pragma unroll
      for (int ni = 0; ni < 4; ++ni)
        P[ni] = __builtin_amdgcn_mfma_f32_16x16x32_bf16(aq[ks], bK[ni], P[ni], 0, 0, 0);
    }

    // ---- weight + write P to LDS (own t-rows) ----
#pragma unroll
    for (int ni = 0; ni < 4; ++ni) {
      const int s = ni * 16 + fr;
#pragma unroll
      for (int r = 0; r < 4; ++r) {
        const int t = wt0 + fg * 4 + r;
        float v = (sb == 0) ? P[ni][r] * LAM128
                : (sb == 1) ? P[ni][r] * LAM64
                            : ((s < t) ? P[ni][r] : 0.f);
        Pl[t * 72 + s] = f2bf(v);
      }
    }
    __syncthreads();  // P ready; all Kl reads done
    if (sb + 1 < 3) STAGE(s0 + 64);  // async stage overlaps PV

    // ---- mem += P @ V_sb : all 64 t-rows x own 64 e-cols ----
#pragma unroll
    for (int ks2 = 0; ks2 < 2; ++ks2) {
      bf16x8 ap[4];
#pragma unroll
      for (int mi = 0; mi < 4; ++mi)
        ap[mi] = *(const bf16x8*)(Pl + (mi * 16 + fr) * 72 + ks2 * 32 + fg * 8);
      const int tk = s0 + ks2 * 32 + fg * 8;
#pragma unroll
      for (int ni = 0; ni < 4; ++ni) {
        bf16x8 bV = *(const bf16x8*)(vTb + (size_t)(ew + ni * 16 + fr) * SEQL + tk);
#pragma unroll
        for (int mi = 0; mi < 4; ++mi)
          mem[mi][ni] = __builtin_amdgcn_mfma_f32_16x16x32_bf16(ap[mi], bV,
                                                               mem[mi][ni], 0, 0, 0);
      }
    }
  }
#undef STAGE

  // store mems bf16: all 64 t x own e-stripe
#pragma unroll
  for (int mi = 0; mi < 4; ++mi)
#pragma unroll
    for (int ni = 0; ni < 4; ++ni)
#pragma unroll
      for (int r = 0; r < 4; ++r) {
        const int t = t0 + mi * 16 + fg * 4 + r;
        mb[(size_t)t * DIMD + ew + ni * 16 + fr] = f2bf(mem[mi][ni][r]);
      }
}

extern "C" void kernel_launch(void* const* d_in, const int* in_sizes, int n_in,
                              void* d_out, int out_size, void* d_ws,
                              size_t ws_size, hipStream_t stream) {
  const float* x  = (const float*)d_in[0];
  const float* Wk = (const float*)d_in[1];
  const float* bk = (const float*)d_in[2];
  const float* Wv = (const float*)d_in[3];
  const float* bv = (const float*)d_in[4];
  const float* Wq = (const float*)d_in[5];
  const float* bq = (const float*)d_in[6];
  const float* Wo = (const float*)d_in[7];
  const float* bo = (const float*)d_in[8];

  float* outp = (float*)d_out;
  float* fstate = outp + KVQ_ELEMS;

  // ws layout (~86 MB < 100.7 proven):
  unsigned short* qhb = (unsigned short*)d_ws;          // q_hat [b][t][d]
  unsigned short* khb = qhb + KVQ_ELEMS;                // k_hat [b][t][d]
  unsigned short* khT = qhb + 2 * KVQ_ELEMS;            // k_hat^T [b][d][t] (t>=1792 only)
  unsigned short* vTp = qhb + 3 * KVQ_ELEMS;            // v^T [b][e][t]
  unsigned short* mbf = qhb + 4 * KVQ_ELEMS;            // mems bf16 [b][t][e]
  unsigned short* WT  = qhb + 5 * KVQ_ELEMS;            // W^T bf16 x4

  // pre-scan scratch inside d_out (dead until out-gemm writes it):
  unsigned short* Abf = (unsigned short*)d_out;         // x bf16 (16.8 MB)

  // 1) x -> bf16  +  W -> W^T bf16 (merged)
  prep<<<dim3(9216), 256, 0, stream>>>(x, Abf, Wq, Wk, Wv, Wo, WT);
  // 2) projections (K=512, BK=32 -> nkt=16) -> q_hat, k_hat(+T trimmed), v^T bf16
  mfma_gemm<0><<<dim3(128, 4, 3), 256, 0, stream>>>(
      Abf, 512, WT /*Wq*/, WT + WSLAB /*Wk*/, WT + 2 * WSLAB /*Wv*/, 512,
      bq, bk, bv, nullptr, qhb, khb, khT, vTp, 16);
  // 3) banded attention -> mems bf16 (blocks 0..511) + final_state (512..639)
  battn<<<dim3(640), 256, 0, stream>>>(qhb, khb, vTp, khT, mbf, fstate);
  // 4) out = mems @ Wo + bo (K=512, nkt=16)
  mfma_gemm<1><<<dim3(128, 4, 1), 256, 0, stream>>>(
      mbf, 512, WT + 3 * WSLAB, WT + 3 * WSLAB, WT + 3 * WSLAB, 512,
      bo, bo, bo, outp, nullptr, nullptr, nullptr, nullptr, 16);
}